// Round 6
// baseline (655.274 us; speedup 1.0000x reference)
//
#include <hip/hip_runtime.h>
#include <hip/hip_bf16.h>
#include <math.h>

// Problem constants
#define BB    4
#define TT    1024
#define EE    256
#define HIDD  256
#define LLUT  8
#define HGT   384
#define WID   384
#define HWPX  147456      // 384*384
#define GSZ   33
#define G3    35937       // 33^3
#define NCOL  862488      // L*3*G3

typedef __attribute__((ext_vector_type(8))) short bf16x8;   // 8 bf16 = 4 VGPRs
typedef __attribute__((ext_vector_type(4))) float f32x4;

// fast gelu (tanh form): max abs dev from exact erf-gelu ~1e-3, threshold 2e-2
__device__ __forceinline__ float gelu_f(float x) {
    float s = 1.5957691216057308f * x * (1.0f + 0.044715f * x * x);
    float e = __expf(s);
    return x - x / (e + 1.0f);   // x*sigmoid(s); safe at +-inf
}

__device__ __forceinline__ ushort f2bf(float x) {
    uint u = __float_as_uint(x);
    return (ushort)((u + 0x7FFFu + ((u >> 16) & 1u)) >> 16);   // RNE
}
__device__ __forceinline__ uint pack2bf(float a, float b) {
    return (uint)f2bf(a) | ((uint)f2bf(b) << 16);
}
__device__ __forceinline__ float bf2f_lo(uint u) { return __uint_as_float(u << 16); }
__device__ __forceinline__ float bf2f_hi(uint u) { return __uint_as_float(u & 0xFFFF0000u); }

// ---------------------------------------------------------------------------
// K0: embedding-mean partial sums. grid (32, B): 32 tokens per block.
// ---------------------------------------------------------------------------
__global__ __launch_bounds__(256) void emb_partial_kernel(
    const int* __restrict__ tokens, const float* __restrict__ emb,
    float* __restrict__ partial)
{
    const int s = blockIdx.x, b = blockIdx.y, tid = threadIdx.x;
    const int* tok = tokens + b * TT + s * 32;
    float acc = 0.f;
#pragma unroll 8
    for (int t = 0; t < 32; ++t) acc += emb[tok[t] * EE + tid];
    partial[(b * 32 + s) * EE + tid] = acc;
}

// ---------------------------------------------------------------------------
// K1: fused token head. One block per batch b.
// ---------------------------------------------------------------------------
__global__ __launch_bounds__(256) void mlp_head_kernel(
    const float* __restrict__ partial,
    const float* __restrict__ aw1, const float* __restrict__ ab1,
    const float* __restrict__ aw2, const float* __restrict__ ab2,
    const float* __restrict__ lw1, const float* __restrict__ lb1,
    const float* __restrict__ gw1, const float* __restrict__ gb1,
    const float* __restrict__ gw2, const float* __restrict__ gb2,
    float* __restrict__ h3_out, float* __restrict__ lw_out)
{
    const int b = blockIdx.x;
    const int tid = threadIdx.x;
    __shared__ float tf[256], h1[256], tf2s[256], h4[64], lg[8];

    float acc = 0.f;
#pragma unroll
    for (int s = 0; s < 32; ++s) acc += partial[(b * 32 + s) * EE + tid];
    tf[tid] = acc * (1.0f / TT);
    __syncthreads();

    {   float s = ab1[tid];
        for (int k = 0; k < EE; ++k) s += tf[k] * aw1[k * HIDD + tid];
        h1[tid] = gelu_f(s);
    }
    __syncthreads();
    {   float s = ab2[tid];
        for (int k = 0; k < HIDD; ++k) s += h1[k] * aw2[k * HIDD + tid];
        tf2s[tid] = s;
    }
    __syncthreads();
    {   float s = lb1[tid];
        for (int k = 0; k < HIDD; ++k) s += tf2s[k] * lw1[k * HIDD + tid];
        h3_out[b * HIDD + tid] = gelu_f(s);
    }
    if (tid < 64) {
        float s = gb1[tid];
        for (int k = 0; k < HIDD; ++k) s += tf2s[k] * gw1[k * 64 + tid];
        h4[tid] = gelu_f(s);
    }
    __syncthreads();
    if (tid < LLUT) {
        float s = gb2[tid];
        for (int k = 0; k < 64; ++k) s += h4[k] * gw2[k * LLUT + tid];
        lg[tid] = s;
    }
    __syncthreads();
    if (tid == 0) {
        float m = lg[0];
        for (int i = 1; i < LLUT; ++i) m = fmaxf(m, lg[i]);
        float ssum = 0.f, ex[LLUT];
        for (int i = 0; i < LLUT; ++i) { ex[i] = expf(lg[i] - m); ssum += ex[i]; }
        for (int i = 0; i < LLUT; ++i) lw_out[b * LLUT + i] = ex[i] / ssum;
    }
}

// ---------------------------------------------------------------------------
// K2: big GEMM. Streams 883 MB of w2 once; HBM-bound floor ~140 us.
// ---------------------------------------------------------------------------
__global__ __launch_bounds__(256) void lut_gemm_kernel(
    const float* __restrict__ h3, const float* __restrict__ w2,
    const float* __restrict__ b2, float* __restrict__ lp)
{
    __shared__ float h[BB * HIDD];
    const int tid = threadIdx.x;
    for (int i = tid; i < BB * HIDD; i += 256) h[i] = h3[i];
    __syncthreads();

    const long col = ((long)blockIdx.x * 256 + tid) * 4;
    if (col >= NCOL) return;

    const float4 bias = *(const float4*)(b2 + col);
    float4 a0 = bias, a1 = bias, a2 = bias, a3 = bias;
    const float* wp = w2 + col;
#pragma unroll 4
    for (int k = 0; k < HIDD; ++k) {
        float4 w = *(const float4*)(wp + (long)k * NCOL);
        float h0 = h[k], h1v = h[HIDD + k], h2 = h[2 * HIDD + k], h3v = h[3 * HIDD + k];
        a0.x += h0 * w.x;  a0.y += h0 * w.y;  a0.z += h0 * w.z;  a0.w += h0 * w.w;
        a1.x += h1v * w.x; a1.y += h1v * w.y; a1.z += h1v * w.z; a1.w += h1v * w.w;
        a2.x += h2 * w.x;  a2.y += h2 * w.y;  a2.z += h2 * w.z;  a2.w += h2 * w.w;
        a3.x += h3v * w.x; a3.y += h3v * w.y; a3.z += h3v * w.z; a3.w += h3v * w.w;
    }
    *(float4*)(lp + 0L * NCOL + col) = a0;
    *(float4*)(lp + 1L * NCOL + col) = a1;
    *(float4*)(lp + 2L * NCOL + col) = a2;
    *(float4*)(lp + 3L * NCOL + col) = a3;
}

// ---------------------------------------------------------------------------
// K3: combine 8 LUTs with softmax weights -> one 3-channel LUT per batch.
// ---------------------------------------------------------------------------
__global__ __launch_bounds__(256) void combine_kernel(
    const float* __restrict__ lp, const float* __restrict__ lwv,
    float* __restrict__ clut)
{
    const int v = blockIdx.x * 256 + threadIdx.x;
    const int b = blockIdx.y;
    if (v >= G3) return;
    float w[LLUT];
#pragma unroll
    for (int l = 0; l < LLUT; ++l) w[l] = lwv[b * LLUT + l];
#pragma unroll
    for (int c = 0; c < 3; ++c) {
        float s = 0.f;
#pragma unroll
        for (int l = 0; l < LLUT; ++l)
            s += w[l] * lp[(long)b * NCOL + (long)(l * 3 + c) * G3 + v];
        clut[(long)(b * 3 + c) * G3 + v] = s;
    }
}

// ---------------------------------------------------------------------------
// K4+K7 merged: trilinear LUT apply (slots 0..2) + 32->3 proc conv from act2
// (slots 4..6) -> comb [px][8] fp32. One kernel = one less launch gap.
// ---------------------------------------------------------------------------
__global__ __launch_bounds__(256) void applylut_out3_kernel(
    const float* __restrict__ clut, const float* __restrict__ recon,
    const ushort* __restrict__ act2, const float* __restrict__ wgt,
    const float* __restrict__ bias, float* __restrict__ comb)
{
    const int p = blockIdx.x * 256 + threadIdx.x;
    const int b = blockIdx.y;

    // --- LUT part ---
    const float* rc = recon + (long)b * 3 * HWPX;
    float cr = fminf(fmaxf(rc[p] * 32.f, 0.f), 32.f);
    float cg = fminf(fmaxf(rc[HWPX + p] * 32.f, 0.f), 32.f);
    float cb = fminf(fmaxf(rc[2 * HWPX + p] * 32.f, 0.f), 32.f);
    float fr = fminf(floorf(cr), 31.f);
    float fg = fminf(floorf(cg), 31.f);
    float fb = fminf(floorf(cb), 31.f);
    float tr = cr - fr, tg = cg - fg, tb_ = cb - fb;
    int idx = (((int)fr * GSZ + (int)fg) * GSZ + (int)fb);
    float c[3];
#pragma unroll
    for (int ch = 0; ch < 3; ++ch) {
        const float* lut = clut + (long)(b * 3 + ch) * G3;
        float v000 = lut[idx],                  v001 = lut[idx + 1];
        float v010 = lut[idx + GSZ],            v011 = lut[idx + GSZ + 1];
        float v100 = lut[idx + GSZ * GSZ],      v101 = lut[idx + GSZ * GSZ + 1];
        float v110 = lut[idx + GSZ * GSZ + GSZ], v111 = lut[idx + GSZ * GSZ + GSZ + 1];
        float c00 = v000 + (v001 - v000) * tb_;
        float c01 = v010 + (v011 - v010) * tb_;
        float c10 = v100 + (v101 - v100) * tb_;
        float c11 = v110 + (v111 - v110) * tb_;
        float c0 = c00 + (c01 - c00) * tg;
        float c1 = c10 + (c11 - c10) * tg;
        c[ch] = c0 + (c1 - c0) * tr;
    }
    float4 r4; r4.x = c[0]; r4.y = c[1]; r4.z = c[2]; r4.w = 0.f;
    *(float4*)(comb + ((long)b * HWPX + p) * 8) = r4;

    // --- proc 32->3 conv part ---
    const int hh = p / WID, ww = p - hh * WID;
    float acc[3] = {bias[0], bias[1], bias[2]};
#pragma unroll
    for (int tap = 0; tap < 9; ++tap) {
        const int dh = tap / 3, dw = tap - dh * 3;
        const int gh = hh + dh - 1, gw = ww + dw - 1;
        if (gh < 0 || gh >= HGT || gw < 0 || gw >= WID) continue;
        const uint4* xp = (const uint4*)(act2 + ((long)b * HWPX + gh * WID + gw) * 32);
        float xx[32];
#pragma unroll
        for (int q = 0; q < 4; ++q) {
            uint4 v = xp[q];
            xx[q * 8 + 0] = bf2f_lo(v.x); xx[q * 8 + 1] = bf2f_hi(v.x);
            xx[q * 8 + 2] = bf2f_lo(v.y); xx[q * 8 + 3] = bf2f_hi(v.y);
            xx[q * 8 + 4] = bf2f_lo(v.z); xx[q * 8 + 5] = bf2f_hi(v.z);
            xx[q * 8 + 6] = bf2f_lo(v.w); xx[q * 8 + 7] = bf2f_hi(v.w);
        }
#pragma unroll
        for (int o = 0; o < 3; ++o)
#pragma unroll
            for (int ci = 0; ci < 32; ++ci)
                acc[o] += xx[ci] * wgt[o * 288 + ci * 9 + tap];
    }
    float4 s4; s4.x = acc[0]; s4.y = acc[1]; s4.z = acc[2]; s4.w = 0.f;
    *(float4*)(comb + ((long)b * HWPX + p) * 8 + 4) = s4;
}

// ---------------------------------------------------------------------------
// K5: 3->32 conv (img fp32 NCHW -> act NHWC bf16), gelu. 2 px/thread.
// ---------------------------------------------------------------------------
__global__ __launch_bounds__(256) void conv_in3_kernel(
    const float* __restrict__ img, const float* __restrict__ wgt,
    const float* __restrict__ bias, ushort* __restrict__ out)
{
    const int tid = threadIdx.x;
    const int p0 = (blockIdx.x * 256 + tid) * 2;
    const int b = blockIdx.y;
    const int hh = p0 / WID, ww = p0 - hh * WID;

    float acc[32][2];
#pragma unroll
    for (int o = 0; o < 32; ++o) { float bv = bias[o]; acc[o][0] = bv; acc[o][1] = bv; }

    const bool wlo = (ww > 0), whi = (ww + 2 < WID);
#pragma unroll
    for (int ci = 0; ci < 3; ++ci) {
        const float* ip = img + (long)(b * 3 + ci) * HWPX;
        float x[3][4];
#pragma unroll
        for (int dh = 0; dh < 3; ++dh) {
            const int hs = hh + dh - 1;
            const bool hok = (hs >= 0) && (hs < HGT);
            const float* rp_ = ip + hs * WID + ww;
            x[dh][0] = (hok && wlo) ? rp_[-1] : 0.f;
            x[dh][1] = hok ? rp_[0] : 0.f;
            x[dh][2] = hok ? rp_[1] : 0.f;
            x[dh][3] = (hok && whi) ? rp_[2] : 0.f;
        }
#pragma unroll
        for (int o = 0; o < 32; ++o) {
            const float* wv = wgt + o * 27 + ci * 9;   // uniform -> s_load
#pragma unroll
            for (int dh = 0; dh < 3; ++dh)
#pragma unroll
                for (int dw = 0; dw < 3; ++dw) {
                    const float w = wv[dh * 3 + dw];
                    acc[o][0] += x[dh][dw]     * w;
                    acc[o][1] += x[dh][dw + 1] * w;
                }
        }
    }

    ushort* op = out + ((long)b * HWPX + p0) * 32;
#pragma unroll
    for (int px = 0; px < 2; ++px) {
        uint u[16];
#pragma unroll
        for (int o2 = 0; o2 < 16; ++o2)
            u[o2] = pack2bf(gelu_f(acc[2 * o2][px]), gelu_f(acc[2 * o2 + 1][px]));
        uint4* dst = (uint4*)(op + px * 32);
#pragma unroll
        for (int q = 0; q < 4; ++q)
            dst[q] = make_uint4(u[4 * q], u[4 * q + 1], u[4 * q + 2], u[4 * q + 3]);
    }
}

// ---------------------------------------------------------------------------
// K6 v3: MFMA 32->32 conv, GLOBAL-DIRECT B loads (no halo staging, no stage
// barrier). act rows are L2-resident across a tile-row sweep (Common-mistake
// #7: don't LDS-stage L2-fit data). Per-lane B addr (gh*384+gw)*32+kg*8 ->
// a wave's 64 lanes read one contiguous 1KB line (coalesced). LDS holds only
// the repacked A-frags (18.4 KB) -> ~6 blocks/CU TLP. A-frags hoisted to 72
// VGPRs. XCD-chunked bijective swizzle (1152 blocks = 8 XCD x 144): each XCD
// keeps its own contiguous band of tile-rows hot in its private L2.
// Tile 8 rows x 64 px, 8 waves, 1 row/wave.
// mfma_f32_16x16x32_bf16: A=W[cout][cin] (row=l&15,k=(l>>4)*8+j),
// B=pixels (col=l&15,k likewise), D: col(px)=l&15, row(cout)=(l>>4)*4+reg.
// ---------------------------------------------------------------------------
#define TH2 8
#define TW2 64
#define NTX (WID / TW2)          // 6
#define NTY (HGT / TH2)          // 48
#define NBLK (NTX * NTY * BB)    // 1152
#define CHUNK (NBLK / 8)         // 144

template <bool HAS_RES>
__global__ __launch_bounds__(512, 2) void conv32_mfma_g(
    const ushort* __restrict__ in, const ushort* __restrict__ res,
    const float* __restrict__ wgt, const float* __restrict__ bias,
    const float* __restrict__ bn_g, const float* __restrict__ bn_bt,
    ushort* __restrict__ out)
{
    __shared__ ushort wlA[9 * 2 * 64 * 8];   // 18432 B, lane-linear A-frags
    __shared__ float s_scale[32], s_shift[32];

    const int tid = threadIdx.x;
    // XCD-chunked bijective swizzle: 1152 = 8 * 144
    const int bid = blockIdx.x;
    const int t   = (bid & 7) * CHUNK + (bid >> 3);
    const int tx  = t % NTX;
    const int rem = t / NTX;
    const int ty  = rem % NTY;
    const int b   = rem / NTY;
    const int h0 = ty * TH2, w0 = tx * TW2;

    // pack A-frags: wlA[((tap*2+half)*64 + lane)*8 + j]
    //   = bf16( W[cout = half*16 + (lane&15)][cin = (lane>>4)*8 + j][tap] )
    for (int i = tid; i < 9 * 2 * 64 * 8; i += 512) {
        const int j    = i & 7;
        const int lane_= (i >> 3) & 63;
        const int half = (i >> 9) & 1;
        const int tap  = i >> 10;
        const int co = half * 16 + (lane_ & 15);
        const int ci = (lane_ >> 4) * 8 + j;
        wlA[i] = f2bf(wgt[co * 288 + ci * 9 + tap]);
    }
    if (tid < 32) {
        float sg = bn_g[tid] * 0.9999950000375f;   // g*(1+1e-5)^-0.5
        s_scale[tid] = sg;
        s_shift[tid] = bias[tid] * sg + bn_bt[tid];
    }
    __syncthreads();

    const int lane = tid & 63, wid = tid >> 6;
    const int l15 = lane & 15, kg = lane >> 4;
    const int gh_base = h0 + wid;              // one output row per wave
    const ushort* inb = in + (long)b * HWPX * 32;

    // hoist all A fragments into registers (2 halves x 9 taps = 72 VGPRs)
    bf16x8 A0[9], A1[9];
#pragma unroll
    for (int tap = 0; tap < 9; ++tap) {
        A0[tap] = *(const bf16x8*)(&wlA[((tap * 2 + 0) * 64 + lane) * 8]);
        A1[tap] = *(const bf16x8*)(&wlA[((tap * 2 + 1) * 64 + lane) * 8]);
    }

    f32x4 acc[4][2];
#pragma unroll
    for (int f = 0; f < 4; ++f)
#pragma unroll
        for (int cf = 0; cf < 2; ++cf)
            acc[f][cf] = (f32x4){0.f, 0.f, 0.f, 0.f};

    const bf16x8 zv = {0, 0, 0, 0, 0, 0, 0, 0};
#pragma unroll
    for (int tap = 0; tap < 9; ++tap) {
        const int dh = tap / 3, dw = tap - dh * 3;
        const int gh = gh_base + dh - 1;
        const bool hok = (gh >= 0) && (gh < HGT);
        const ushort* rowp = inb + (long)gh * (WID * 32) + kg * 8;
#pragma unroll
        for (int f = 0; f < 4; ++f) {
            const int gw = w0 + f * 16 + dw + l15 - 1;
            bf16x8 bv = zv;
            if (hok && gw >= 0 && gw < WID)
                bv = *(const bf16x8*)(rowp + gw * 32);
            acc[f][0] = __builtin_amdgcn_mfma_f32_16x16x32_bf16(A0[tap], bv, acc[f][0], 0, 0, 0);
            acc[f][1] = __builtin_amdgcn_mfma_f32_16x16x32_bf16(A1[tap], bv, acc[f][1], 0, 0, 0);
        }
    }

    // epilogue: scale/shift (+res) + gelu -> bf16 NHWC
#pragma unroll
    for (int f = 0; f < 4; ++f) {
        const int c0 = f * 16;
        const long gpx = (long)b * HWPX + (long)gh_base * WID + (w0 + c0 + l15);
#pragma unroll
        for (int cf = 0; cf < 2; ++cf) {
            const int co0 = cf * 16 + kg * 4;
            const float4 sc = *(const float4*)(&s_scale[co0]);
            const float4 sh = *(const float4*)(&s_shift[co0]);
            float v0 = acc[f][cf][0] * sc.x + sh.x;
            float v1 = acc[f][cf][1] * sc.y + sh.y;
            float v2 = acc[f][cf][2] * sc.z + sh.z;
            float v3 = acc[f][cf][3] * sc.w + sh.w;
            if (HAS_RES) {
                const uint2 rv = *(const uint2*)(res + gpx * 32 + co0);
                v0 += bf2f_lo(rv.x); v1 += bf2f_hi(rv.x);
                v2 += bf2f_lo(rv.y); v3 += bf2f_hi(rv.y);
            }
            uint2 o;
            o.x = pack2bf(gelu_f(v0), gelu_f(v1));
            o.y = pack2bf(gelu_f(v2), gelu_f(v3));
            *(uint2*)(out + gpx * 32 + co0) = o;
        }
    }
}

// ---------------------------------------------------------------------------
// K8: 6->32 conv (comb fp32 [px][8] -> act NHWC bf16), gelu. 1 px/thread.
// slots {0,1,2} = fused (w ci 0..2), slots {4,5,6} = proc (w ci 3..5).
// ---------------------------------------------------------------------------
__global__ __launch_bounds__(256) void conv_in6_kernel(
    const float* __restrict__ comb, const float* __restrict__ wgt,
    const float* __restrict__ bias, ushort* __restrict__ out)
{
    const int p = blockIdx.x * 256 + threadIdx.x;
    const int b = blockIdx.y;
    const int hh = p / WID, ww = p - hh * WID;

    float acc[32];
#pragma unroll
    for (int o = 0; o < 32; ++o) acc[o] = bias[o];

#pragma unroll
    for (int tap = 0; tap < 9; ++tap) {
        const int dh = tap / 3, dw = tap - dh * 3;
        const int gh = hh + dh - 1, gw = ww + dw - 1;
        if (gh < 0 || gh >= HGT || gw < 0 || gw >= WID) continue;
        const float4* cp = (const float4*)(comb + ((long)b * HWPX + gh * WID + gw) * 8);
        const float4 qa = cp[0], qb = cp[1];
        const float xs[6] = {qa.x, qa.y, qa.z, qb.x, qb.y, qb.z};
#pragma unroll
        for (int o = 0; o < 32; ++o) {
            const float* wv = wgt + o * 54 + tap;   // uniform -> s_load
            acc[o] += xs[0] * wv[0]  + xs[1] * wv[9]  + xs[2] * wv[18]
                    + xs[3] * wv[27] + xs[4] * wv[36] + xs[5] * wv[45];
        }
    }

    ushort* op = out + ((long)b * HWPX + p) * 32;
    uint u[16];
#pragma unroll
    for (int o2 = 0; o2 < 16; ++o2)
        u[o2] = pack2bf(gelu_f(acc[2 * o2]), gelu_f(acc[2 * o2 + 1]));
    uint4* dst = (uint4*)op;
#pragma unroll
    for (int q = 0; q < 4; ++q)
        dst[q] = make_uint4(u[4 * q], u[4 * q + 1], u[4 * q + 2], u[4 * q + 3]);
}

// ---------------------------------------------------------------------------
// K9: final 32->3 conv (NHWC bf16) + img -> d_out fp32 NCHW. 1 px/thread.
// ---------------------------------------------------------------------------
__global__ __launch_bounds__(256) void conv_final_kernel(
    const ushort* __restrict__ in, const float* __restrict__ wgt,
    const float* __restrict__ bias, const float* __restrict__ img,
    float* __restrict__ outp)
{
    const int p = blockIdx.x * 256 + threadIdx.x;
    const int b = blockIdx.y;
    const int hh = p / WID, ww = p - hh * WID;
    float acc[3] = {bias[0], bias[1], bias[2]};

#pragma unroll
    for (int tap = 0; tap < 9; ++tap) {
        const int dh = tap / 3, dw = tap - dh * 3;
        const int gh = hh + dh - 1, gw = ww + dw - 1;
        if (gh < 0 || gh >= HGT || gw < 0 || gw >= WID) continue;
        const uint4* xp = (const uint4*)(in + ((long)b * HWPX + gh * WID + gw) * 32);
        float xx[32];
#pragma unroll
        for (int q = 0; q < 4; ++q) {
            uint4 v = xp[q];
            xx[q * 8 + 0] = bf2f_lo(v.x); xx[q * 8 + 1] = bf2f_hi(v.x);
            xx[q * 8 + 2] = bf2f_lo(v.y); xx[q * 8 + 3] = bf2f_hi(v.y);
            xx[q * 8 + 4] = bf2f_lo(v.z); xx[q * 8 + 5] = bf2f_hi(v.z);
            xx[q * 8 + 6] = bf2f_lo(v.w); xx[q * 8 + 7] = bf2f_hi(v.w);
        }
#pragma unroll
        for (int o = 0; o < 3; ++o)
#pragma unroll
            for (int ci = 0; ci < 32; ++ci)
                acc[o] += xx[ci] * wgt[o * 288 + ci * 9 + tap];
    }
#pragma unroll
    for (int o = 0; o < 3; ++o)
        outp[(long)(b * 3 + o) * HWPX + p] = acc[o] + img[(long)(b * 3 + o) * HWPX + p];
}

// ---------------------------------------------------------------------------
extern "C" void kernel_launch(void* const* d_in, const int* in_sizes, int n_in,
                              void* d_out, int out_size, void* d_ws, size_t ws_size,
                              hipStream_t stream)
{
    const int*   tokens  = (const int*)d_in[0];
    const float* img     = (const float*)d_in[1];
    const float* recon   = (const float*)d_in[2];
    const float* emb     = (const float*)d_in[3];
    const float* agg_w1  = (const float*)d_in[4];
    const float* agg_b1  = (const float*)d_in[5];
    const float* agg_w2  = (const float*)d_in[6];
    const float* agg_b2  = (const float*)d_in[7];
    const float* lut_w1  = (const float*)d_in[8];
    const float* lut_b1  = (const float*)d_in[9];
    const float* lut_w2  = (const float*)d_in[10];
    const float* lut_b2  = (const float*)d_in[11];
    const float* wg_w1   = (const float*)d_in[12];
    const float* wg_b1   = (const float*)d_in[13];
    const float* wg_w2   = (const float*)d_in[14];
    const float* wg_b2   = (const float*)d_in[15];
    const float* rp_cin_w = (const float*)d_in[16];
    const float* rp_cin_b = (const float*)d_in[17];
    const float* rp_rbA_w = (const float*)d_in[18];
    const float* rp_rbA_b = (const float*)d_in[19];
    const float* rp_rbA_g = (const float*)d_in[20];
    const float* rp_rbA_bt= (const float*)d_in[21];
    const float* rp_rbB_w = (const float*)d_in[22];
    const float* rp_rbB_b = (const float*)d_in[23];
    const float* rp_rbB_g = (const float*)d_in[24];
    const float* rp_rbB_bt= (const float*)d_in[25];
    const float* rp_cout_w= (const float*)d_in[26];
    const float* rp_cout_b= (const float*)d_in[27];
    const float* fu_cin_w = (const float*)d_in[28];
    const float* fu_cin_b = (const float*)d_in[29];
    const float* fu_rbA_w = (const float*)d_in[30];
    const float* fu_rbA_b = (const float*)d_in[31];
    const float* fu_rbA_g = (const float*)d_in[32];
    const float* fu_rbA_bt= (const float*)d_in[33];
    const float* fu_rbB_w = (const float*)d_in[34];
    const float* fu_rbB_b = (const float*)d_in[35];
    const float* fu_rbB_g = (const float*)d_in[36];
    const float* fu_rbB_bt= (const float*)d_in[37];
    const float* fu_cout_w= (const float*)d_in[38];
    const float* fu_cout_b= (const float*)d_in[39];

    float* ws = (float*)d_ws;
    float*  h3      = ws;                      // 1024
    float*  lwv     = ws + 1024;               // 32
    float*  partial = ws + 2048;               // 32768
    float*  lp      = ws + 40960;              // 3449952
    float*  clut    = ws + 3491840;            // 431244
    float*  comb    = ws + 3932160;            // 4718592  ([px][8] fp32)
    ushort* act0    = (ushort*)(ws + 8650752); // 18874368 ushorts
    ushort* act1    = (ushort*)(ws + 18087936);
    ushort* act2    = (ushort*)(ws + 27525120);
    float*  outp    = (float*)d_out;

    // token head
    emb_partial_kernel<<<dim3(32, BB), dim3(256), 0, stream>>>(tokens, emb, partial);
    mlp_head_kernel<<<dim3(BB), dim3(256), 0, stream>>>(
        partial, agg_w1, agg_b1, agg_w2, agg_b2,
        lut_w1, lut_b1, wg_w1, wg_b1, wg_w2, wg_b2, h3, lwv);

    // LUT path
    lut_gemm_kernel<<<dim3((NCOL / 4 + 255) / 256), dim3(256), 0, stream>>>(
        h3, lut_w2, lut_b2, lp);
    combine_kernel<<<dim3((G3 + 255) / 256, BB), dim3(256), 0, stream>>>(lp, lwv, clut);

    const dim3 g1(HWPX / 256, BB), g2(HWPX / 512, BB), blk(256);
    const dim3 gm(NBLK), bm(512);

    // proc branch: img -> act0 -> act1 -> act2
    conv_in3_kernel<<<g2, blk, 0, stream>>>(img, rp_cin_w, rp_cin_b, act0);
    conv32_mfma_g<false><<<gm, bm, 0, stream>>>(
        act0, nullptr, rp_rbA_w, rp_rbA_b, rp_rbA_g, rp_rbA_bt, act1);
    conv32_mfma_g<true><<<gm, bm, 0, stream>>>(
        act1, act0, rp_rbB_w, rp_rbB_b, rp_rbB_g, rp_rbB_bt, act2);

    // merged: LUT apply + proc 32->3 -> comb
    applylut_out3_kernel<<<g1, blk, 0, stream>>>(
        clut, recon, act2, rp_cout_w, rp_cout_b, comb);

    // fuse branch: comb -> act0 -> act1 -> act2 -> d_out (+img)
    conv_in6_kernel<<<g1, blk, 0, stream>>>(comb, fu_cin_w, fu_cin_b, act0);
    conv32_mfma_g<false><<<gm, bm, 0, stream>>>(
        act0, nullptr, fu_rbA_w, fu_rbA_b, fu_rbA_g, fu_rbA_bt, act1);
    conv32_mfma_g<true><<<gm, bm, 0, stream>>>(
        act1, act0, fu_rbB_w, fu_rbB_b, fu_rbB_g, fu_rbB_bt, act2);
    conv_final_kernel<<<g1, blk, 0, stream>>>(act2, fu_cout_w, fu_cout_b, img, outp);
}

// Round 7
// 563.608 us; speedup vs baseline: 1.1626x; 1.1626x over previous
//
#include <hip/hip_runtime.h>
#include <hip/hip_bf16.h>
#include <math.h>

// Problem constants
#define BB    4
#define TT    1024
#define EE    256
#define HIDD  256
#define LLUT  8
#define HGT   384
#define WID   384
#define HWPX  147456      // 384*384
#define GSZ   33
#define G3    35937       // 33^3
#define NCOL  862488      // L*3*G3

typedef __attribute__((ext_vector_type(8))) short bf16x8;   // 8 bf16 = 4 VGPRs
typedef __attribute__((ext_vector_type(4))) float f32x4;

// fast gelu (tanh form): max abs dev from exact erf-gelu ~1e-3, threshold 2e-2
__device__ __forceinline__ float gelu_f(float x) {
    float s = 1.5957691216057308f * x * (1.0f + 0.044715f * x * x);
    float e = __expf(s);
    return x - x / (e + 1.0f);   // x*sigmoid(s); safe at +-inf
}

__device__ __forceinline__ ushort f2bf(float x) {
    uint u = __float_as_uint(x);
    return (ushort)((u + 0x7FFFu + ((u >> 16) & 1u)) >> 16);   // RNE
}
__device__ __forceinline__ uint pack2bf(float a, float b) {
    return (uint)f2bf(a) | ((uint)f2bf(b) << 16);
}
__device__ __forceinline__ float bf2f_lo(uint u) { return __uint_as_float(u << 16); }
__device__ __forceinline__ float bf2f_hi(uint u) { return __uint_as_float(u & 0xFFFF0000u); }

// ---------------------------------------------------------------------------
// K0: embedding-mean partial sums. grid (64, B): 16 tokens per block -> 1
// block/CU spread.
// ---------------------------------------------------------------------------
__global__ __launch_bounds__(256) void emb_partial_kernel(
    const int* __restrict__ tokens, const float* __restrict__ emb,
    float* __restrict__ partial)
{
    const int s = blockIdx.x, b = blockIdx.y, tid = threadIdx.x;
    const int* tok = tokens + b * TT + s * 16;
    float acc = 0.f;
#pragma unroll
    for (int t = 0; t < 16; ++t) acc += emb[tok[t] * EE + tid];
    partial[(b * 64 + s) * EE + tid] = acc;
}

// ---------------------------------------------------------------------------
// K1 v2: fused token head, latency-parallel. 1024 threads/block, 1 block per
// batch. Each 256x256 GEMV stage: 4 threads per output (64-k slices each,
// unroll 8 -> 8 loads in flight) + LDS tree reduce. Fixes the r5 structure
// where 256-iter un-unrolled loops exposed full memory latency per iteration
// at 1 wave/SIMD (~100+ us hidden in a "small" kernel).
// ---------------------------------------------------------------------------
__global__ __launch_bounds__(1024) void mlp_head_kernel(
    const float* __restrict__ partial,
    const float* __restrict__ aw1, const float* __restrict__ ab1,
    const float* __restrict__ aw2, const float* __restrict__ ab2,
    const float* __restrict__ lw1, const float* __restrict__ lb1,
    const float* __restrict__ gw1, const float* __restrict__ gb1,
    const float* __restrict__ gw2, const float* __restrict__ gb2,
    float* __restrict__ h3_out, float* __restrict__ lw_out)
{
    const int b = blockIdx.x;
    const int tid = threadIdx.x;          // 0..1023
    const int o = tid & 255;              // output index
    const int q = tid >> 8;               // k-quarter 0..3
    __shared__ float tf[256], h1[256], tf2s[256], h4[64], lg[8];
    __shared__ float red[4][256];

    // embedding mean from 64 partial segments
    {
        float acc = 0.f;
#pragma unroll
        for (int s = 0; s < 16; ++s)
            acc += partial[(b * 64 + q * 16 + s) * EE + o];
        red[q][o] = acc;
    }
    __syncthreads();
    if (tid < 256)
        tf[tid] = (red[0][tid] + red[1][tid] + red[2][tid] + red[3][tid]) * (1.0f / TT);
    __syncthreads();

    // stage 1: h1 = gelu(tf @ aw1 + ab1)
    {
        float s = 0.f;
#pragma unroll 8
        for (int j = 0; j < 64; ++j) {
            const int k = (q << 6) + j;
            s += tf[k] * aw1[k * HIDD + o];
        }
        red[q][o] = s;
    }
    __syncthreads();
    if (tid < 256)
        h1[tid] = gelu_f(red[0][tid] + red[1][tid] + red[2][tid] + red[3][tid] + ab1[tid]);
    __syncthreads();

    // stage 2: tf2 = h1 @ aw2 + ab2
    {
        float s = 0.f;
#pragma unroll 8
        for (int j = 0; j < 64; ++j) {
            const int k = (q << 6) + j;
            s += h1[k] * aw2[k * HIDD + o];
        }
        red[q][o] = s;
    }
    __syncthreads();
    if (tid < 256)
        tf2s[tid] = red[0][tid] + red[1][tid] + red[2][tid] + red[3][tid] + ab2[tid];
    __syncthreads();

    // stage 3: h3 = gelu(tf2 @ lw1 + lb1) -> global
    {
        float s = 0.f;
#pragma unroll 8
        for (int j = 0; j < 64; ++j) {
            const int k = (q << 6) + j;
            s += tf2s[k] * lw1[k * HIDD + o];
        }
        red[q][o] = s;
    }
    __syncthreads();
    if (tid < 256)
        h3_out[b * HIDD + tid] =
            gelu_f(red[0][tid] + red[1][tid] + red[2][tid] + red[3][tid] + lb1[tid]);
    __syncthreads();

    // stage 4a: h4 = gelu(tf2 @ gw1 + gb1): 64 outputs, 16-way k-split
    {
        const int o64 = tid & 63, q16 = tid >> 6;
        float s = 0.f;
#pragma unroll
        for (int j = 0; j < 16; ++j) {
            const int k = q16 * 16 + j;
            s += tf2s[k] * gw1[k * 64 + o64];
        }
        ((float*)red)[q16 * 64 + o64] = s;
    }
    __syncthreads();
    if (tid < 64) {
        float s = gb1[tid];
#pragma unroll
        for (int r = 0; r < 16; ++r) s += ((float*)red)[r * 64 + tid];
        h4[tid] = gelu_f(s);
    }
    __syncthreads();

    // stage 4b: lg = h4 @ gw2 + gb2 (8 outputs, K=64 from LDS)
    if (tid < 8) {
        float s = gb2[tid];
#pragma unroll 8
        for (int k = 0; k < 64; ++k) s += h4[k] * gw2[k * LLUT + tid];
        lg[tid] = s;
    }
    __syncthreads();
    if (tid == 0) {
        float m = lg[0];
        for (int i = 1; i < LLUT; ++i) m = fmaxf(m, lg[i]);
        float ssum = 0.f, ex[LLUT];
        for (int i = 0; i < LLUT; ++i) { ex[i] = expf(lg[i] - m); ssum += ex[i]; }
        for (int i = 0; i < LLUT; ++i) lw_out[b * LLUT + i] = ex[i] / ssum;
    }
}

// ---------------------------------------------------------------------------
// K2: big GEMM. Streams 883 MB of w2 once; HBM-bound floor ~140 us.
// ---------------------------------------------------------------------------
__global__ __launch_bounds__(256) void lut_gemm_kernel(
    const float* __restrict__ h3, const float* __restrict__ w2,
    const float* __restrict__ b2, float* __restrict__ lp)
{
    __shared__ float h[BB * HIDD];
    const int tid = threadIdx.x;
    for (int i = tid; i < BB * HIDD; i += 256) h[i] = h3[i];
    __syncthreads();

    const long col = ((long)blockIdx.x * 256 + tid) * 4;
    if (col >= NCOL) return;

    const float4 bias = *(const float4*)(b2 + col);
    float4 a0 = bias, a1 = bias, a2 = bias, a3 = bias;
    const float* wp = w2 + col;
#pragma unroll 4
    for (int k = 0; k < HIDD; ++k) {
        float4 w = *(const float4*)(wp + (long)k * NCOL);
        float h0 = h[k], h1v = h[HIDD + k], h2 = h[2 * HIDD + k], h3v = h[3 * HIDD + k];
        a0.x += h0 * w.x;  a0.y += h0 * w.y;  a0.z += h0 * w.z;  a0.w += h0 * w.w;
        a1.x += h1v * w.x; a1.y += h1v * w.y; a1.z += h1v * w.z; a1.w += h1v * w.w;
        a2.x += h2 * w.x;  a2.y += h2 * w.y;  a2.z += h2 * w.z;  a2.w += h2 * w.w;
        a3.x += h3v * w.x; a3.y += h3v * w.y; a3.z += h3v * w.z; a3.w += h3v * w.w;
    }
    *(float4*)(lp + 0L * NCOL + col) = a0;
    *(float4*)(lp + 1L * NCOL + col) = a1;
    *(float4*)(lp + 2L * NCOL + col) = a2;
    *(float4*)(lp + 3L * NCOL + col) = a3;
}

// ---------------------------------------------------------------------------
// K3: combine 8 LUTs with softmax weights -> one 3-channel LUT per batch.
// ---------------------------------------------------------------------------
__global__ __launch_bounds__(256) void combine_kernel(
    const float* __restrict__ lp, const float* __restrict__ lwv,
    float* __restrict__ clut)
{
    const int v = blockIdx.x * 256 + threadIdx.x;
    const int b = blockIdx.y;
    if (v >= G3) return;
    float w[LLUT];
#pragma unroll
    for (int l = 0; l < LLUT; ++l) w[l] = lwv[b * LLUT + l];
#pragma unroll
    for (int c = 0; c < 3; ++c) {
        float s = 0.f;
#pragma unroll
        for (int l = 0; l < LLUT; ++l)
            s += w[l] * lp[(long)b * NCOL + (long)(l * 3 + c) * G3 + v];
        clut[(long)(b * 3 + c) * G3 + v] = s;
    }
}

// ---------------------------------------------------------------------------
// K4+K7 merged: trilinear LUT apply (slots 0..2) + 32->3 proc conv from act2
// (slots 4..6) -> comb [px][8] fp32.
// ---------------------------------------------------------------------------
__global__ __launch_bounds__(256) void applylut_out3_kernel(
    const float* __restrict__ clut, const float* __restrict__ recon,
    const ushort* __restrict__ act2, const float* __restrict__ wgt,
    const float* __restrict__ bias, float* __restrict__ comb)
{
    const int p = blockIdx.x * 256 + threadIdx.x;
    const int b = blockIdx.y;

    // --- LUT part ---
    const float* rc = recon + (long)b * 3 * HWPX;
    float cr = fminf(fmaxf(rc[p] * 32.f, 0.f), 32.f);
    float cg = fminf(fmaxf(rc[HWPX + p] * 32.f, 0.f), 32.f);
    float cb = fminf(fmaxf(rc[2 * HWPX + p] * 32.f, 0.f), 32.f);
    float fr = fminf(floorf(cr), 31.f);
    float fg = fminf(floorf(cg), 31.f);
    float fb = fminf(floorf(cb), 31.f);
    float tr = cr - fr, tg = cg - fg, tb_ = cb - fb;
    int idx = (((int)fr * GSZ + (int)fg) * GSZ + (int)fb);
    float c[3];
#pragma unroll
    for (int ch = 0; ch < 3; ++ch) {
        const float* lut = clut + (long)(b * 3 + ch) * G3;
        float v000 = lut[idx],                  v001 = lut[idx + 1];
        float v010 = lut[idx + GSZ],            v011 = lut[idx + GSZ + 1];
        float v100 = lut[idx + GSZ * GSZ],      v101 = lut[idx + GSZ * GSZ + 1];
        float v110 = lut[idx + GSZ * GSZ + GSZ], v111 = lut[idx + GSZ * GSZ + GSZ + 1];
        float c00 = v000 + (v001 - v000) * tb_;
        float c01 = v010 + (v011 - v010) * tb_;
        float c10 = v100 + (v101 - v100) * tb_;
        float c11 = v110 + (v111 - v110) * tb_;
        float c0 = c00 + (c01 - c00) * tg;
        float c1 = c10 + (c11 - c10) * tg;
        c[ch] = c0 + (c1 - c0) * tr;
    }
    float4 r4; r4.x = c[0]; r4.y = c[1]; r4.z = c[2]; r4.w = 0.f;
    *(float4*)(comb + ((long)b * HWPX + p) * 8) = r4;

    // --- proc 32->3 conv part ---
    const int hh = p / WID, ww = p - hh * WID;
    float acc[3] = {bias[0], bias[1], bias[2]};
#pragma unroll
    for (int tap = 0; tap < 9; ++tap) {
        const int dh = tap / 3, dw = tap - dh * 3;
        const int gh = hh + dh - 1, gw = ww + dw - 1;
        if (gh < 0 || gh >= HGT || gw < 0 || gw >= WID) continue;
        const uint4* xp = (const uint4*)(act2 + ((long)b * HWPX + gh * WID + gw) * 32);
        float xx[32];
#pragma unroll
        for (int q = 0; q < 4; ++q) {
            uint4 v = xp[q];
            xx[q * 8 + 0] = bf2f_lo(v.x); xx[q * 8 + 1] = bf2f_hi(v.x);
            xx[q * 8 + 2] = bf2f_lo(v.y); xx[q * 8 + 3] = bf2f_hi(v.y);
            xx[q * 8 + 4] = bf2f_lo(v.z); xx[q * 8 + 5] = bf2f_hi(v.z);
            xx[q * 8 + 6] = bf2f_lo(v.w); xx[q * 8 + 7] = bf2f_hi(v.w);
        }
#pragma unroll
        for (int o = 0; o < 3; ++o)
#pragma unroll
            for (int ci = 0; ci < 32; ++ci)
                acc[o] += xx[ci] * wgt[o * 288 + ci * 9 + tap];
    }
    float4 s4; s4.x = acc[0]; s4.y = acc[1]; s4.z = acc[2]; s4.w = 0.f;
    *(float4*)(comb + ((long)b * HWPX + p) * 8 + 4) = s4;
}

// ---------------------------------------------------------------------------
// K5: 3->32 conv (img fp32 NCHW -> act NHWC bf16), gelu. 2 px/thread.
// ---------------------------------------------------------------------------
__global__ __launch_bounds__(256) void conv_in3_kernel(
    const float* __restrict__ img, const float* __restrict__ wgt,
    const float* __restrict__ bias, ushort* __restrict__ out)
{
    const int tid = threadIdx.x;
    const int p0 = (blockIdx.x * 256 + tid) * 2;
    const int b = blockIdx.y;
    const int hh = p0 / WID, ww = p0 - hh * WID;

    float acc[32][2];
#pragma unroll
    for (int o = 0; o < 32; ++o) { float bv = bias[o]; acc[o][0] = bv; acc[o][1] = bv; }

    const bool wlo = (ww > 0), whi = (ww + 2 < WID);
#pragma unroll
    for (int ci = 0; ci < 3; ++ci) {
        const float* ip = img + (long)(b * 3 + ci) * HWPX;
        float x[3][4];
#pragma unroll
        for (int dh = 0; dh < 3; ++dh) {
            const int hs = hh + dh - 1;
            const bool hok = (hs >= 0) && (hs < HGT);
            const float* rp_ = ip + hs * WID + ww;
            x[dh][0] = (hok && wlo) ? rp_[-1] : 0.f;
            x[dh][1] = hok ? rp_[0] : 0.f;
            x[dh][2] = hok ? rp_[1] : 0.f;
            x[dh][3] = (hok && whi) ? rp_[2] : 0.f;
        }
#pragma unroll
        for (int o = 0; o < 32; ++o) {
            const float* wv = wgt + o * 27 + ci * 9;   // uniform -> s_load
#pragma unroll
            for (int dh = 0; dh < 3; ++dh)
#pragma unroll
                for (int dw = 0; dw < 3; ++dw) {
                    const float w = wv[dh * 3 + dw];
                    acc[o][0] += x[dh][dw]     * w;
                    acc[o][1] += x[dh][dw + 1] * w;
                }
        }
    }

    ushort* op = out + ((long)b * HWPX + p0) * 32;
#pragma unroll
    for (int px = 0; px < 2; ++px) {
        uint u[16];
#pragma unroll
        for (int o2 = 0; o2 < 16; ++o2)
            u[o2] = pack2bf(gelu_f(acc[2 * o2][px]), gelu_f(acc[2 * o2 + 1][px]));
        uint4* dst = (uint4*)(op + px * 32);
#pragma unroll
        for (int q = 0; q < 4; ++q)
            dst[q] = make_uint4(u[4 * q], u[4 * q + 1], u[4 * q + 2], u[4 * q + 3]);
    }
}

// ---------------------------------------------------------------------------
// K6 (r5 version, empirically best): MFMA 32->32 conv, staged LDS halo.
// Tile 8 rows x 64 px, 8 waves (1 row/wave). Halo 10x66 px, CSTR=40 ushort
// pad (conflict-free b128). A-frags lane-linear in LDS. 71.3 KB -> 2
// blocks/CU.
// ---------------------------------------------------------------------------
#define TH2 8
#define TW2 64
#define HALO_H2 10
#define HALO_W2 66
#define CSTR 40   // padded ushort stride per pixel (80 B)

template <bool HAS_RES>
__global__ __launch_bounds__(512, 4) void conv32_mfma(
    const ushort* __restrict__ in, const ushort* __restrict__ res,
    const float* __restrict__ wgt, const float* __restrict__ bias,
    const float* __restrict__ bn_g, const float* __restrict__ bn_bt,
    ushort* __restrict__ out)
{
    __shared__ ushort halo[HALO_H2 * HALO_W2 * CSTR];   // 52800 B
    __shared__ ushort wlA[9 * 2 * 64 * 8];              // 18432 B, lane-linear
    __shared__ float s_scale[32], s_shift[32];

    const int tid = threadIdx.x;
    const int b  = blockIdx.z;
    const int h0 = blockIdx.y * TH2;
    const int w0 = blockIdx.x * TW2;

    // pack A-frags: wlA[((tap*2+half)*64 + lane)*8 + j]
    for (int i = tid; i < 9 * 2 * 64 * 8; i += 512) {
        const int j    = i & 7;
        const int lane_= (i >> 3) & 63;
        const int half = (i >> 9) & 1;
        const int tap  = i >> 10;
        const int co = half * 16 + (lane_ & 15);
        const int ci = (lane_ >> 4) * 8 + j;
        wlA[i] = f2bf(wgt[co * 288 + ci * 9 + tap]);
    }
    if (tid < 32) {
        float sg = bn_g[tid] * 0.9999950000375f;   // g*(1+1e-5)^-0.5
        s_scale[tid] = sg;
        s_shift[tid] = bias[tid] * sg + bn_bt[tid];
    }

    // stage halo (zero-filled OOB); 16B chunks, coalesced NHWC reads
    const ushort* inb = in + (long)b * HWPX * 32;
    for (int i = tid; i < HALO_H2 * HALO_W2 * 4; i += 512) {
        const int row = i / (HALO_W2 * 4);
        const int rem = i - row * (HALO_W2 * 4);
        const int px = rem >> 2, q = rem & 3;
        const int gh = h0 + row - 1, gw = w0 + px - 1;
        uint4 v = make_uint4(0u, 0u, 0u, 0u);
        if (gh >= 0 && gh < HGT && gw >= 0 && gw < WID)
            v = *(const uint4*)(inb + ((long)gh * WID + gw) * 32 + q * 8);
        *(uint4*)(&halo[(row * HALO_W2 + px) * CSTR + q * 8]) = v;
    }
    __syncthreads();

    const int lane = tid & 63, wid = tid >> 6;
    const int l15 = lane & 15, kg = lane >> 4;
    const int r = wid;                      // one output row per wave

    f32x4 acc[4][2];
#pragma unroll
    for (int f = 0; f < 4; ++f)
#pragma unroll
        for (int cf = 0; cf < 2; ++cf)
            acc[f][cf] = (f32x4){0.f, 0.f, 0.f, 0.f};

#pragma unroll
    for (int tap = 0; tap < 9; ++tap) {
        const int dh = tap / 3, dw = tap - dh * 3;
        const bf16x8 a0 = *(const bf16x8*)(&wlA[((tap * 2 + 0) * 64 + lane) * 8]);
        const bf16x8 a1 = *(const bf16x8*)(&wlA[((tap * 2 + 1) * 64 + lane) * 8]);
#pragma unroll
        for (int f = 0; f < 4; ++f) {
            const int c0 = f * 16;
            const bf16x8 bfv = *(const bf16x8*)(
                &halo[((r + dh) * HALO_W2 + (c0 + dw + l15)) * CSTR + kg * 8]);
            acc[f][0] = __builtin_amdgcn_mfma_f32_16x16x32_bf16(a0, bfv, acc[f][0], 0, 0, 0);
            acc[f][1] = __builtin_amdgcn_mfma_f32_16x16x32_bf16(a1, bfv, acc[f][1], 0, 0, 0);
        }
    }

    // epilogue: scale/shift (+res) + gelu -> bf16 NHWC
#pragma unroll
    for (int f = 0; f < 4; ++f) {
        const int c0 = f * 16;
        const long gpx = (long)b * HWPX + (long)(h0 + r) * WID + (w0 + c0 + l15);
#pragma unroll
        for (int cf = 0; cf < 2; ++cf) {
            const int co0 = cf * 16 + kg * 4;
            const float4 sc = *(const float4*)(&s_scale[co0]);
            const float4 sh = *(const float4*)(&s_shift[co0]);
            float v0 = acc[f][cf][0] * sc.x + sh.x;
            float v1 = acc[f][cf][1] * sc.y + sh.y;
            float v2 = acc[f][cf][2] * sc.z + sh.z;
            float v3 = acc[f][cf][3] * sc.w + sh.w;
            if (HAS_RES) {
                const uint2 rv = *(const uint2*)(res + gpx * 32 + co0);
                v0 += bf2f_lo(rv.x); v1 += bf2f_hi(rv.x);
                v2 += bf2f_lo(rv.y); v3 += bf2f_hi(rv.y);
            }
            uint2 o;
            o.x = pack2bf(gelu_f(v0), gelu_f(v1));
            o.y = pack2bf(gelu_f(v2), gelu_f(v3));
            *(uint2*)(out + gpx * 32 + co0) = o;
        }
    }
}

// ---------------------------------------------------------------------------
// K8: 6->32 conv (comb fp32 [px][8] -> act NHWC bf16), gelu. 1 px/thread.
// ---------------------------------------------------------------------------
__global__ __launch_bounds__(256) void conv_in6_kernel(
    const float* __restrict__ comb, const float* __restrict__ wgt,
    const float* __restrict__ bias, ushort* __restrict__ out)
{
    const int p = blockIdx.x * 256 + threadIdx.x;
    const int b = blockIdx.y;
    const int hh = p / WID, ww = p - hh * WID;

    float acc[32];
#pragma unroll
    for (int o = 0; o < 32; ++o) acc[o] = bias[o];

#pragma unroll
    for (int tap = 0; tap < 9; ++tap) {
        const int dh = tap / 3, dw = tap - dh * 3;
        const int gh = hh + dh - 1, gw = ww + dw - 1;
        if (gh < 0 || gh >= HGT || gw < 0 || gw >= WID) continue;
        const float4* cp = (const float4*)(comb + ((long)b * HWPX + gh * WID + gw) * 8);
        const float4 qa = cp[0], qb = cp[1];
        const float xs[6] = {qa.x, qa.y, qa.z, qb.x, qb.y, qb.z};
#pragma unroll
        for (int o = 0; o < 32; ++o) {
            const float* wv = wgt + o * 54 + tap;   // uniform -> s_load
            acc[o] += xs[0] * wv[0]  + xs[1] * wv[9]  + xs[2] * wv[18]
                    + xs[3] * wv[27] + xs[4] * wv[36] + xs[5] * wv[45];
        }
    }

    ushort* op = out + ((long)b * HWPX + p) * 32;
    uint u[16];
#pragma unroll
    for (int o2 = 0; o2 < 16; ++o2)
        u[o2] = pack2bf(gelu_f(acc[2 * o2]), gelu_f(acc[2 * o2 + 1]));
    uint4* dst = (uint4*)op;
#pragma unroll
    for (int q = 0; q < 4; ++q)
        dst[q] = make_uint4(u[4 * q], u[4 * q + 1], u[4 * q + 2], u[4 * q + 3]);
}

// ---------------------------------------------------------------------------
// K9: final 32->3 conv (NHWC bf16) + img -> d_out fp32 NCHW. 1 px/thread.
// ---------------------------------------------------------------------------
__global__ __launch_bounds__(256) void conv_final_kernel(
    const ushort* __restrict__ in, const float* __restrict__ wgt,
    const float* __restrict__ bias, const float* __restrict__ img,
    float* __restrict__ outp)
{
    const int p = blockIdx.x * 256 + threadIdx.x;
    const int b = blockIdx.y;
    const int hh = p / WID, ww = p - hh * WID;
    float acc[3] = {bias[0], bias[1], bias[2]};

#pragma unroll
    for (int tap = 0; tap < 9; ++tap) {
        const int dh = tap / 3, dw = tap - dh * 3;
        const int gh = hh + dh - 1, gw = ww + dw - 1;
        if (gh < 0 || gh >= HGT || gw < 0 || gw >= WID) continue;
        const uint4* xp = (const uint4*)(in + ((long)b * HWPX + gh * WID + gw) * 32);
        float xx[32];
#pragma unroll
        for (int q = 0; q < 4; ++q) {
            uint4 v = xp[q];
            xx[q * 8 + 0] = bf2f_lo(v.x); xx[q * 8 + 1] = bf2f_hi(v.x);
            xx[q * 8 + 2] = bf2f_lo(v.y); xx[q * 8 + 3] = bf2f_hi(v.y);
            xx[q * 8 + 4] = bf2f_lo(v.z); xx[q * 8 + 5] = bf2f_hi(v.z);
            xx[q * 8 + 6] = bf2f_lo(v.w); xx[q * 8 + 7] = bf2f_hi(v.w);
        }
#pragma unroll
        for (int o = 0; o < 3; ++o)
#pragma unroll
            for (int ci = 0; ci < 32; ++ci)
                acc[o] += xx[ci] * wgt[o * 288 + ci * 9 + tap];
    }
#pragma unroll
    for (int o = 0; o < 3; ++o)
        outp[(long)(b * 3 + o) * HWPX + p] = acc[o] + img[(long)(b * 3 + o) * HWPX + p];
}

// ---------------------------------------------------------------------------
extern "C" void kernel_launch(void* const* d_in, const int* in_sizes, int n_in,
                              void* d_out, int out_size, void* d_ws, size_t ws_size,
                              hipStream_t stream)
{
    const int*   tokens  = (const int*)d_in[0];
    const float* img     = (const float*)d_in[1];
    const float* recon   = (const float*)d_in[2];
    const float* emb     = (const float*)d_in[3];
    const float* agg_w1  = (const float*)d_in[4];
    const float* agg_b1  = (const float*)d_in[5];
    const float* agg_w2  = (const float*)d_in[6];
    const float* agg_b2  = (const float*)d_in[7];
    const float* lut_w1  = (const float*)d_in[8];
    const float* lut_b1  = (const float*)d_in[9];
    const float* lut_w2  = (const float*)d_in[10];
    const float* lut_b2  = (const float*)d_in[11];
    const float* wg_w1   = (const float*)d_in[12];
    const float* wg_b1   = (const float*)d_in[13];
    const float* wg_w2   = (const float*)d_in[14];
    const float* wg_b2   = (const float*)d_in[15];
    const float* rp_cin_w = (const float*)d_in[16];
    const float* rp_cin_b = (const float*)d_in[17];
    const float* rp_rbA_w = (const float*)d_in[18];
    const float* rp_rbA_b = (const float*)d_in[19];
    const float* rp_rbA_g = (const float*)d_in[20];
    const float* rp_rbA_bt= (const float*)d_in[21];
    const float* rp_rbB_w = (const float*)d_in[22];
    const float* rp_rbB_b = (const float*)d_in[23];
    const float* rp_rbB_g = (const float*)d_in[24];
    const float* rp_rbB_bt= (const float*)d_in[25];
    const float* rp_cout_w= (const float*)d_in[26];
    const float* rp_cout_b= (const float*)d_in[27];
    const float* fu_cin_w = (const float*)d_in[28];
    const float* fu_cin_b = (const float*)d_in[29];
    const float* fu_rbA_w = (const float*)d_in[30];
    const float* fu_rbA_b = (const float*)d_in[31];
    const float* fu_rbA_g = (const float*)d_in[32];
    const float* fu_rbA_bt= (const float*)d_in[33];
    const float* fu_rbB_w = (const float*)d_in[34];
    const float* fu_rbB_b = (const float*)d_in[35];
    const float* fu_rbB_g = (const float*)d_in[36];
    const float* fu_rbB_bt= (const float*)d_in[37];
    const float* fu_cout_w= (const float*)d_in[38];
    const float* fu_cout_b= (const float*)d_in[39];

    float* ws = (float*)d_ws;
    float*  h3      = ws;                      // 1024
    float*  lwv     = ws + 1024;               // 32
    float*  partial = ws + 2048;               // 65536 (4 x 64 x 256)
    float*  lp      = ws + 69632;              // 3449952
    float*  clut    = ws + 3519584;            // 431244
    float*  comb    = ws + 3952640;            // 4718592  ([px][8] fp32)
    ushort* act0    = (ushort*)(ws + 8675328); // 18874368 ushorts
    ushort* act1    = (ushort*)(ws + 18112512);
    ushort* act2    = (ushort*)(ws + 27549696);
    float*  outp    = (float*)d_out;

    // token head (parallel gather + latency-parallel MLP)
    emb_partial_kernel<<<dim3(64, BB), dim3(256), 0, stream>>>(tokens, emb, partial);
    mlp_head_kernel<<<dim3(BB), dim3(1024), 0, stream>>>(
        partial, agg_w1, agg_b1, agg_w2, agg_b2,
        lut_w1, lut_b1, wg_w1, wg_b1, wg_w2, wg_b2, h3, lwv);

    // LUT path
    lut_gemm_kernel<<<dim3((NCOL / 4 + 255) / 256), dim3(256), 0, stream>>>(
        h3, lut_w2, lut_b2, lp);
    combine_kernel<<<dim3((G3 + 255) / 256, BB), dim3(256), 0, stream>>>(lp, lwv, clut);

    const dim3 g1(HWPX / 256, BB), g2(HWPX / 512, BB), blk(256);
    const dim3 gm(WID / TW2, HGT / TH2, BB), bm(512);

    // proc branch: img -> act0 -> act1 -> act2
    conv_in3_kernel<<<g2, blk, 0, stream>>>(img, rp_cin_w, rp_cin_b, act0);
    conv32_mfma<false><<<gm, bm, 0, stream>>>(
        act0, nullptr, rp_rbA_w, rp_rbA_b, rp_rbA_g, rp_rbA_bt, act1);
    conv32_mfma<true><<<gm, bm, 0, stream>>>(
        act1, act0, rp_rbB_w, rp_rbB_b, rp_rbB_g, rp_rbB_bt, act2);

    // merged: LUT apply + proc 32->3 -> comb
    applylut_out3_kernel<<<g1, blk, 0, stream>>>(
        clut, recon, act2, rp_cout_w, rp_cout_b, comb);

    // fuse branch: comb -> act0 -> act1 -> act2 -> d_out (+img)
    conv_in6_kernel<<<g1, blk, 0, stream>>>(comb, fu_cin_w, fu_cin_b, act0);
    conv32_mfma<false><<<gm, bm, 0, stream>>>(
        act0, nullptr, fu_rbA_w, fu_rbA_b, fu_rbA_g, fu_rbA_bt, act1);
    conv32_mfma<true><<<gm, bm, 0, stream>>>(
        act1, act0, fu_rbB_w, fu_rbB_b, fu_rbB_g, fu_rbB_bt, act2);
    conv_final_kernel<<<g1, blk, 0, stream>>>(act2, fu_cout_w, fu_cout_b, img, outp);
}